// Round 1
// baseline (145.395 us; speedup 1.0000x reference)
//
#include <hip/hip_runtime.h>
#include <math.h>

#define WTHRESH 0.5f
#define EPSV    1e-5f

// One Jacobi rotation on symmetric A (p,q) with third index r, accumulating V.
// app=a[p][p], aqq=a[q][q], apq=a[p][q], arp=a[r][p], arq=a[r][q],
// v?p / v?q are the V entries of columns p and q (rows 0,1,2).
#define JROT(app,aqq,apq, arp,arq, vAp,vAq, vBp,vBq, vCp,vCq)                 \
  do {                                                                        \
    float _apq = (apq);                                                       \
    if (fabsf(_apq) > 1e-30f) {                                               \
      float _tau = ((aqq) - (app)) * 0.5f / _apq;                             \
      float _t = copysignf(1.0f, _tau) / (fabsf(_tau) + sqrtf(1.0f + _tau*_tau)); \
      float _c = 1.0f / sqrtf(1.0f + _t*_t);                                  \
      float _s = _t * _c;                                                     \
      float _app = (app), _aqq = (aqq);                                       \
      (app) = _app - _t * _apq;                                               \
      (aqq) = _aqq + _t * _apq;                                               \
      (apq) = 0.0f;                                                           \
      float _arp = (arp), _arq = (arq);                                       \
      (arp) = _c * _arp - _s * _arq;                                          \
      (arq) = _s * _arp + _c * _arq;                                          \
      { float _vp=(vAp), _vq=(vAq); (vAp)=_c*_vp-_s*_vq; (vAq)=_s*_vp+_c*_vq; } \
      { float _vp=(vBp), _vq=(vBq); (vBp)=_c*_vp-_s*_vq; (vBq)=_s*_vp+_c*_vq; } \
      { float _vp=(vCp), _vq=(vCq); (vCp)=_c*_vp-_s*_vq; (vCq)=_s*_vp+_c*_vq; } \
    }                                                                         \
  } while (0)

// descending sort swap of eigenpair (li, col x0y0z0) vs (lj, col x1y1z1)
#define CSWAP(li,lj, x0,x1, y0,y1, z0,z1)                                     \
  do { if ((li) < (lj)) {                                                     \
    float _t;                                                                 \
    _t=(li); (li)=(lj); (lj)=_t;                                              \
    _t=(x0); (x0)=(x1); (x1)=_t;                                              \
    _t=(y0); (y0)=(y1); (y1)=_t;                                              \
    _t=(z0); (z0)=(z1); (z1)=_t;                                              \
  } } while (0)

__global__ __launch_bounds__(256) void wproc_kernel(
    const float* __restrict__ src, const float* __restrict__ tgt,
    const float* __restrict__ wts, float* __restrict__ outR,
    float* __restrict__ outT)
{
  const int b   = blockIdx.x;
  const int tid = threadIdx.x;

  // batch bases: src/tgt are (N=1024, 3) f32 -> 3072 floats (16B-aligned),
  // weights 1024 floats. Each thread handles 4 consecutive points:
  // floats [12*tid, 12*tid+12) -> float4 indices 3*tid .. 3*tid+2.
  const float4* s4 = reinterpret_cast<const float4*>(src + (size_t)b * 3072);
  const float4* t4 = reinterpret_cast<const float4*>(tgt + (size_t)b * 3072);
  const float4* w4 = reinterpret_cast<const float4*>(wts + (size_t)b * 1024);

  float4 sA = s4[3*tid+0], sB = s4[3*tid+1], sC = s4[3*tid+2];
  float4 tA = t4[3*tid+0], tB = t4[3*tid+1], tC = t4[3*tid+2];
  float4 wv = w4[tid];

  // acc: [0]=S, [1..3]=Sum w*src, [4..6]=Sum w*ref, [7..15]=Sum w*src_i*ref_j
  float acc[16];
  #pragma unroll
  for (int k = 0; k < 16; ++k) acc[k] = 0.0f;

  float PX[4][3] = {{sA.x,sA.y,sA.z},{sA.w,sB.x,sB.y},{sB.z,sB.w,sC.x},{sC.y,sC.z,sC.w}};
  float PY[4][3] = {{tA.x,tA.y,tA.z},{tA.w,tB.x,tB.y},{tB.z,tB.w,tC.x},{tC.y,tC.z,tC.w}};
  float WW[4]    = {wv.x, wv.y, wv.z, wv.w};

  #pragma unroll
  for (int k = 0; k < 4; ++k) {
    float w  = (WW[k] < WTHRESH) ? 0.0f : WW[k];
    float x0 = PX[k][0], x1 = PX[k][1], x2 = PX[k][2];
    float y0 = PY[k][0], y1 = PY[k][1], y2 = PY[k][2];
    acc[0] += w;
    acc[1] += w*x0; acc[2] += w*x1; acc[3] += w*x2;
    acc[4] += w*y0; acc[5] += w*y1; acc[6] += w*y2;
    float wx0 = w*x0, wx1 = w*x1, wx2 = w*x2;
    acc[7]  += wx0*y0; acc[8]  += wx0*y1; acc[9]  += wx0*y2;
    acc[10] += wx1*y0; acc[11] += wx1*y1; acc[12] += wx1*y2;
    acc[13] += wx2*y0; acc[14] += wx2*y1; acc[15] += wx2*y2;
  }

  // wave (64-lane) reduction
  #pragma unroll
  for (int off = 32; off > 0; off >>= 1) {
    #pragma unroll
    for (int k = 0; k < 16; ++k) acc[k] += __shfl_down(acc[k], off, 64);
  }

  __shared__ float red[4][16];
  const int wave = tid >> 6;
  const int lane = tid & 63;
  if (lane == 0) {
    #pragma unroll
    for (int k = 0; k < 16; ++k) red[wave][k] = acc[k];
  }
  __syncthreads();
  if (tid != 0) return;

  float f[16];
  #pragma unroll
  for (int k = 0; k < 16; ++k) f[k] = red[0][k] + red[1][k] + red[2][k] + red[3][k];

  // normalized quantities
  const float inv  = 1.0f / (f[0] + EPSV);
  const float cx0 = f[1]*inv, cx1 = f[2]*inv, cx2 = f[3]*inv;   // src centroid
  const float cy0 = f[4]*inv, cy1 = f[5]*inv, cy2 = f[6]*inv;   // ref centroid
  const float ssum = f[0] * inv;            // sum of normalized weights (~1)
  const float g = 2.0f - ssum;

  // H[i][j] = M[i][j]*inv - g * cx_i * cy_j
  float H00 = f[7]*inv  - g*cx0*cy0, H01 = f[8]*inv  - g*cx0*cy1, H02 = f[9]*inv  - g*cx0*cy2;
  float H10 = f[10]*inv - g*cx1*cy0, H11 = f[11]*inv - g*cx1*cy1, H12 = f[12]*inv - g*cx1*cy2;
  float H20 = f[13]*inv - g*cx2*cy0, H21 = f[14]*inv - g*cx2*cy1, H22 = f[15]*inv - g*cx2*cy2;

  // A = H^T H (symmetric)
  float a00 = H00*H00 + H10*H10 + H20*H20;
  float a11 = H01*H01 + H11*H11 + H21*H21;
  float a22 = H02*H02 + H12*H12 + H22*H22;
  float a01 = H00*H01 + H10*H11 + H20*H21;
  float a02 = H00*H02 + H10*H12 + H20*H22;
  float a12 = H01*H02 + H11*H12 + H21*H22;

  float v00=1.f,v01=0.f,v02=0.f, v10=0.f,v11=1.f,v12=0.f, v20=0.f,v21=0.f,v22=1.f;

  #pragma unroll
  for (int sweep = 0; sweep < 8; ++sweep) {
    JROT(a00,a11,a01, a02,a12, v00,v01, v10,v11, v20,v21);   // (p,q)=(0,1)
    JROT(a00,a22,a02, a01,a12, v00,v02, v10,v12, v20,v22);   // (p,q)=(0,2)
    JROT(a11,a22,a12, a01,a02, v01,v02, v11,v12, v21,v22);   // (p,q)=(1,2)
  }

  // sort eigenpairs descending (columns of V follow)
  CSWAP(a00,a11, v00,v01, v10,v11, v20,v21);
  CSWAP(a00,a22, v00,v02, v10,v12, v20,v22);
  CSWAP(a11,a22, v01,v02, v11,v12, v21,v22);

  // U columns: u_k = H v_k, then normalize (sigma_k = |H v_k|)
  float u00 = H00*v00 + H01*v10 + H02*v20;
  float u10 = H10*v00 + H11*v10 + H12*v20;
  float u20 = H20*v00 + H21*v10 + H22*v20;
  float u01 = H00*v01 + H01*v11 + H02*v21;
  float u11 = H10*v01 + H11*v11 + H12*v21;
  float u21 = H20*v01 + H21*v11 + H22*v21;
  float u02 = H00*v02 + H01*v12 + H02*v22;
  float u12 = H10*v02 + H11*v12 + H12*v22;
  float u22 = H20*v02 + H21*v12 + H22*v22;

  float n0 = sqrtf(u00*u00 + u10*u10 + u20*u20);
  float n1 = sqrtf(u01*u01 + u11*u11 + u21*u21);
  float n2 = sqrtf(u02*u02 + u12*u12 + u22*u22);

  float R00,R01,R02,R10,R11,R12,R20,R21,R22;

  if (n0 < 1e-20f) {
    // H ~ 0: numpy svd(0) gives U=I, Vh=I, det=1 -> R=I
    R00=1.f;R01=0.f;R02=0.f; R10=0.f;R11=1.f;R12=0.f; R20=0.f;R21=0.f;R22=1.f;
  } else {
    float i0 = 1.0f / n0;
    u00*=i0; u10*=i0; u20*=i0;

    if (n1 > 1e-7f * n0) {
      float i1 = 1.0f / n1;
      u01*=i1; u11*=i1; u21*=i1;
    } else {
      // arbitrary unit vector perpendicular to u0
      float ax = fabsf(u00), ay = fabsf(u10), az = fabsf(u20);
      float e0,e1,e2;
      if (ax <= ay && ax <= az)      { e0=1.f; e1=0.f; e2=0.f; }
      else if (ay <= az)             { e0=0.f; e1=1.f; e2=0.f; }
      else                           { e0=0.f; e1=0.f; e2=1.f; }
      u01 = u10*e2 - u20*e1;
      u11 = u20*e0 - u00*e2;
      u21 = u00*e1 - u10*e0;
      float nn = 1.0f / sqrtf(u01*u01 + u11*u11 + u21*u21);
      u01*=nn; u11*=nn; u21*=nn;
    }

    if (n2 > 1e-7f * n0) {
      float i2 = 1.0f / n2;
      u02*=i2; u12*=i2; u22*=i2;
    } else {
      // u2 = u0 x u1 (orthonormal completion)
      u02 = u10*u21 - u20*u11;
      u12 = u20*u01 - u00*u21;
      u22 = u00*u11 - u10*u01;
    }

    float detU = u00*(u11*u22 - u12*u21) - u01*(u10*u22 - u12*u20) + u02*(u10*u21 - u11*u20);
    float detV = v00*(v11*v22 - v12*v21) - v01*(v10*v22 - v12*v20) + v02*(v10*v21 - v11*v20);
    float sgn = (detU * detV < 0.0f) ? -1.0f : 1.0f;

    // R = V diag(1,1,sgn) U^T ; R[i][j] = v_i0*u_j0 + v_i1*u_j1 + sgn*v_i2*u_j2
    R00 = v00*u00 + v01*u01 + sgn*v02*u02;
    R01 = v00*u10 + v01*u11 + sgn*v02*u12;
    R02 = v00*u20 + v01*u21 + sgn*v02*u22;
    R10 = v10*u00 + v11*u01 + sgn*v12*u02;
    R11 = v10*u10 + v11*u11 + sgn*v12*u12;
    R12 = v10*u20 + v11*u21 + sgn*v12*u22;
    R20 = v20*u00 + v21*u01 + sgn*v22*u02;
    R21 = v20*u10 + v21*u11 + sgn*v22*u12;
    R22 = v20*u20 + v21*u21 + sgn*v22*u22;
  }

  float t0 = cy0 - (R00*cx0 + R01*cx1 + R02*cx2);
  float t1 = cy1 - (R10*cx0 + R11*cx1 + R12*cx2);
  float t2 = cy2 - (R20*cx0 + R21*cx1 + R22*cx2);

  float* Rb = outR + (size_t)b * 9;
  Rb[0]=R00; Rb[1]=R01; Rb[2]=R02;
  Rb[3]=R10; Rb[4]=R11; Rb[5]=R12;
  Rb[6]=R20; Rb[7]=R21; Rb[8]=R22;
  float* tb = outT + (size_t)b * 3;
  tb[0]=t0; tb[1]=t1; tb[2]=t2;
}

extern "C" void kernel_launch(void* const* d_in, const int* in_sizes, int n_in,
                              void* d_out, int out_size, void* d_ws, size_t ws_size,
                              hipStream_t stream) {
  const float* src = (const float*)d_in[0];
  const float* tgt = (const float*)d_in[1];
  const float* w   = (const float*)d_in[2];

  const int B = in_sizes[2] / 1024;   // N = 1024 points per batch
  float* outR = (float*)d_out;              // (B,3,3)
  float* outT = outR + (size_t)B * 9;       // (B,3)

  wproc_kernel<<<dim3(B), dim3(256), 0, stream>>>(src, tgt, w, outR, outT);
}

// Round 3
// 140.656 us; speedup vs baseline: 1.0337x; 1.0337x over previous
//
#include <hip/hip_runtime.h>
#include <math.h>

#define WTHRESH 0.5f
#define EPSV    1e-5f

// ---- wave64 DPP sum: result in lane 63 (rocPRIM-style row_shr + row_bcast) ----
template <int CTRL>
__device__ __forceinline__ float dpp_add(float x) {
  int xi = __builtin_bit_cast(int, x);
  int mv = __builtin_amdgcn_update_dpp(0, xi, CTRL, 0xF, 0xF, true);
  return x + __builtin_bit_cast(float, mv);
}

// One Jacobi rotation on symmetric A (p,q) with third index r, accumulating V.
#define JROT(app,aqq,apq, arp,arq, vAp,vAq, vBp,vBq, vCp,vCq)                 \
  do {                                                                        \
    float _apq = (apq);                                                       \
    if (fabsf(_apq) > 1e-30f) {                                               \
      float _tau = ((aqq) - (app)) * 0.5f / _apq;                             \
      float _t = copysignf(1.0f, _tau) / (fabsf(_tau) + sqrtf(1.0f + _tau*_tau)); \
      float _c = 1.0f / sqrtf(1.0f + _t*_t);                                  \
      float _s = _t * _c;                                                     \
      float _app = (app), _aqq = (aqq);                                       \
      (app) = _app - _t * _apq;                                               \
      (aqq) = _aqq + _t * _apq;                                               \
      (apq) = 0.0f;                                                           \
      float _arp = (arp), _arq = (arq);                                       \
      (arp) = _c * _arp - _s * _arq;                                          \
      (arq) = _s * _arp + _c * _arq;                                          \
      { float _vp=(vAp), _vq=(vAq); (vAp)=_c*_vp-_s*_vq; (vAq)=_s*_vp+_c*_vq; } \
      { float _vp=(vBp), _vq=(vBq); (vBp)=_c*_vp-_s*_vq; (vBq)=_s*_vp+_c*_vq; } \
      { float _vp=(vCp), _vq=(vCq); (vCp)=_c*_vp-_s*_vq; (vCq)=_s*_vp+_c*_vq; } \
    }                                                                         \
  } while (0)

#define CSWAP(li,lj, x0,x1, y0,y1, z0,z1)                                     \
  do { if ((li) < (lj)) {                                                     \
    float _t;                                                                 \
    _t=(li); (li)=(lj); (lj)=_t;                                              \
    _t=(x0); (x0)=(x1); (x1)=_t;                                              \
    _t=(y0); (y0)=(y1); (y1)=_t;                                              \
    _t=(z0); (z0)=(z1); (z1)=_t;                                              \
  } } while (0)

// ---------------- kernel 1: per-batch 16-scalar reduction ----------------
// grid = B blocks x 256 threads (4 waves). Each wave writes its 16 partial
// sums (lane 63 after DPP reduce) to ws[(b*4+w)*16 + k]. No LDS, no barrier.
__global__ __launch_bounds__(256) void wproc_reduce(
    const float* __restrict__ src, const float* __restrict__ tgt,
    const float* __restrict__ wts, float* __restrict__ ws)
{
  const int b   = blockIdx.x;
  const int tid = threadIdx.x;

  const float4* s4 = reinterpret_cast<const float4*>(src + (size_t)b * 3072);
  const float4* t4 = reinterpret_cast<const float4*>(tgt + (size_t)b * 3072);
  const float4* w4 = reinterpret_cast<const float4*>(wts + (size_t)b * 1024);

  float4 sA = s4[3*tid+0], sB = s4[3*tid+1], sC = s4[3*tid+2];
  float4 tA = t4[3*tid+0], tB = t4[3*tid+1], tC = t4[3*tid+2];
  float4 wv = w4[tid];

  // acc: [0]=S, [1..3]=Sum w*src, [4..6]=Sum w*ref, [7..15]=Sum w*src_i*ref_j
  float acc[16];
  #pragma unroll
  for (int k = 0; k < 16; ++k) acc[k] = 0.0f;

  float PX[4][3] = {{sA.x,sA.y,sA.z},{sA.w,sB.x,sB.y},{sB.z,sB.w,sC.x},{sC.y,sC.z,sC.w}};
  float PY[4][3] = {{tA.x,tA.y,tA.z},{tA.w,tB.x,tB.y},{tB.z,tB.w,tC.x},{tC.y,tC.z,tC.w}};
  float WW[4]    = {wv.x, wv.y, wv.z, wv.w};

  #pragma unroll
  for (int k = 0; k < 4; ++k) {
    float w  = (WW[k] < WTHRESH) ? 0.0f : WW[k];
    float x0 = PX[k][0], x1 = PX[k][1], x2 = PX[k][2];
    float y0 = PY[k][0], y1 = PY[k][1], y2 = PY[k][2];
    acc[0] += w;
    acc[1] += w*x0; acc[2] += w*x1; acc[3] += w*x2;
    acc[4] += w*y0; acc[5] += w*y1; acc[6] += w*y2;
    float wx0 = w*x0, wx1 = w*x1, wx2 = w*x2;
    acc[7]  += wx0*y0; acc[8]  += wx0*y1; acc[9]  += wx0*y2;
    acc[10] += wx1*y0; acc[11] += wx1*y1; acc[12] += wx1*y2;
    acc[13] += wx2*y0; acc[14] += wx2*y1; acc[15] += wx2*y2;
  }

  // 6-level DPP wave reduction (VALU pipe only); total lands in lane 63
  #pragma unroll
  for (int k = 0; k < 16; ++k) acc[k] = dpp_add<0x111>(acc[k]);  // row_shr:1
  #pragma unroll
  for (int k = 0; k < 16; ++k) acc[k] = dpp_add<0x112>(acc[k]);  // row_shr:2
  #pragma unroll
  for (int k = 0; k < 16; ++k) acc[k] = dpp_add<0x114>(acc[k]);  // row_shr:4
  #pragma unroll
  for (int k = 0; k < 16; ++k) acc[k] = dpp_add<0x118>(acc[k]);  // row_shr:8
  #pragma unroll
  for (int k = 0; k < 16; ++k) acc[k] = dpp_add<0x142>(acc[k]);  // row_bcast:15
  #pragma unroll
  for (int k = 0; k < 16; ++k) acc[k] = dpp_add<0x143>(acc[k]);  // row_bcast:31

  if ((tid & 63) == 63) {
    float* o = ws + ((size_t)b * 4 + (tid >> 6)) * 16;
    #pragma unroll
    for (int k = 0; k < 16; ++k) o[k] = acc[k];
  }
}

// ---------------- kernel 2: per-batch 3x3 SVD, one thread per batch ----------------
__global__ __launch_bounds__(256) void wproc_svd(
    const float* __restrict__ ws, float* __restrict__ outR,
    float* __restrict__ outT, int B)
{
  const int b = blockIdx.x * 256 + threadIdx.x;
  if (b >= B) return;

  const float* p = ws + (size_t)b * 64;
  float f[16];
  #pragma unroll
  for (int k = 0; k < 16; ++k) f[k] = p[k] + p[16 + k] + p[32 + k] + p[48 + k];

  const float inv  = 1.0f / (f[0] + EPSV);
  const float cx0 = f[1]*inv, cx1 = f[2]*inv, cx2 = f[3]*inv;
  const float cy0 = f[4]*inv, cy1 = f[5]*inv, cy2 = f[6]*inv;
  const float ssum = f[0] * inv;
  const float g = 2.0f - ssum;

  float H00 = f[7]*inv  - g*cx0*cy0, H01 = f[8]*inv  - g*cx0*cy1, H02 = f[9]*inv  - g*cx0*cy2;
  float H10 = f[10]*inv - g*cx1*cy0, H11 = f[11]*inv - g*cx1*cy1, H12 = f[12]*inv - g*cx1*cy2;
  float H20 = f[13]*inv - g*cx2*cy0, H21 = f[14]*inv - g*cx2*cy1, H22 = f[15]*inv - g*cx2*cy2;

  float a00 = H00*H00 + H10*H10 + H20*H20;
  float a11 = H01*H01 + H11*H11 + H21*H21;
  float a22 = H02*H02 + H12*H12 + H22*H22;
  float a01 = H00*H01 + H10*H11 + H20*H21;
  float a02 = H00*H02 + H10*H12 + H20*H22;
  float a12 = H01*H02 + H11*H12 + H21*H22;

  float v00=1.f,v01=0.f,v02=0.f, v10=0.f,v11=1.f,v12=0.f, v20=0.f,v21=0.f,v22=1.f;

  #pragma unroll
  for (int sweep = 0; sweep < 8; ++sweep) {
    JROT(a00,a11,a01, a02,a12, v00,v01, v10,v11, v20,v21);
    JROT(a00,a22,a02, a01,a12, v00,v02, v10,v12, v20,v22);
    JROT(a11,a22,a12, a01,a02, v01,v02, v11,v12, v21,v22);
  }

  CSWAP(a00,a11, v00,v01, v10,v11, v20,v21);
  CSWAP(a00,a22, v00,v02, v10,v12, v20,v22);
  CSWAP(a11,a22, v01,v02, v11,v12, v21,v22);

  float u00 = H00*v00 + H01*v10 + H02*v20;
  float u10 = H10*v00 + H11*v10 + H12*v20;
  float u20 = H20*v00 + H21*v10 + H22*v20;
  float u01 = H00*v01 + H01*v11 + H02*v21;
  float u11 = H10*v01 + H11*v11 + H12*v21;
  float u21 = H20*v01 + H21*v11 + H22*v21;
  float u02 = H00*v02 + H01*v12 + H02*v22;
  float u12 = H10*v02 + H11*v12 + H12*v22;
  float u22 = H20*v02 + H21*v12 + H22*v22;

  float n0 = sqrtf(u00*u00 + u10*u10 + u20*u20);
  float n1 = sqrtf(u01*u01 + u11*u11 + u21*u21);
  float n2 = sqrtf(u02*u02 + u12*u12 + u22*u22);

  float R00,R01,R02,R10,R11,R12,R20,R21,R22;

  if (n0 < 1e-20f) {
    R00=1.f;R01=0.f;R02=0.f; R10=0.f;R11=1.f;R12=0.f; R20=0.f;R21=0.f;R22=1.f;
  } else {
    float i0 = 1.0f / n0;
    u00*=i0; u10*=i0; u20*=i0;

    if (n1 > 1e-7f * n0) {
      float i1 = 1.0f / n1;
      u01*=i1; u11*=i1; u21*=i1;
    } else {
      float ax = fabsf(u00), ay = fabsf(u10), az = fabsf(u20);
      float e0,e1,e2;
      if (ax <= ay && ax <= az)      { e0=1.f; e1=0.f; e2=0.f; }
      else if (ay <= az)             { e0=0.f; e1=1.f; e2=0.f; }
      else                           { e0=0.f; e1=0.f; e2=1.f; }
      u01 = u10*e2 - u20*e1;
      u11 = u20*e0 - u00*e2;
      u21 = u00*e1 - u10*e0;
      float nn = 1.0f / sqrtf(u01*u01 + u11*u11 + u21*u21);
      u01*=nn; u11*=nn; u21*=nn;
    }

    if (n2 > 1e-7f * n0) {
      float i2 = 1.0f / n2;
      u02*=i2; u12*=i2; u22*=i2;
    } else {
      u02 = u10*u21 - u20*u11;
      u12 = u20*u01 - u00*u21;
      u22 = u00*u11 - u10*u01;
    }

    float detU = u00*(u11*u22 - u12*u21) - u01*(u10*u22 - u12*u20) + u02*(u10*u21 - u11*u20);
    float detV = v00*(v11*v22 - v12*v21) - v01*(v10*v22 - v12*v20) + v02*(v10*v21 - v11*v20);
    float sgn = (detU * detV < 0.0f) ? -1.0f : 1.0f;

    R00 = v00*u00 + v01*u01 + sgn*v02*u02;
    R01 = v00*u10 + v01*u11 + sgn*v02*u12;
    R02 = v00*u20 + v01*u21 + sgn*v02*u22;
    R10 = v10*u00 + v11*u01 + sgn*v12*u02;
    R11 = v10*u10 + v11*u11 + sgn*v12*u12;
    R12 = v10*u20 + v11*u21 + sgn*v12*u22;
    R20 = v20*u00 + v21*u01 + sgn*v22*u02;
    R21 = v20*u10 + v21*u11 + sgn*v22*u12;
    R22 = v20*u20 + v21*u21 + sgn*v22*u22;
  }

  float t0 = cy0 - (R00*cx0 + R01*cx1 + R02*cx2);
  float t1 = cy1 - (R10*cx0 + R11*cx1 + R12*cx2);
  float t2 = cy2 - (R20*cx0 + R21*cx1 + R22*cx2);

  float* Rb = outR + (size_t)b * 9;
  Rb[0]=R00; Rb[1]=R01; Rb[2]=R02;
  Rb[3]=R10; Rb[4]=R11; Rb[5]=R12;
  Rb[6]=R20; Rb[7]=R21; Rb[8]=R22;
  float* tb = outT + (size_t)b * 3;
  tb[0]=t0; tb[1]=t1; tb[2]=t2;
}

extern "C" void kernel_launch(void* const* d_in, const int* in_sizes, int n_in,
                              void* d_out, int out_size, void* d_ws, size_t ws_size,
                              hipStream_t stream) {
  const float* src = (const float*)d_in[0];
  const float* tgt = (const float*)d_in[1];
  const float* w   = (const float*)d_in[2];

  const int B = in_sizes[2] / 1024;   // N = 1024 points per batch
  float* outR = (float*)d_out;              // (B,3,3)
  float* outT = outR + (size_t)B * 9;       // (B,3)
  float* ws   = (float*)d_ws;               // B*4 waves * 16 partials

  wproc_reduce<<<dim3(B), dim3(256), 0, stream>>>(src, tgt, w, ws);
  wproc_svd<<<dim3((B + 255) / 256), dim3(256), 0, stream>>>(ws, outR, outT, B);
}